// Round 1
// baseline (493.065 us; speedup 1.0000x reference)
//
#include <hip/hip_runtime.h>

// Problem constants (from reference): B=16, H=90, LP=512, W=256, L=256, K=384
#define B_   16
#define H_   90
#define LP_  512
#define WL_  65536   // W*L
#define K_   384
#define BHK  (B_ * H_ * K_)   // 552960

// Zero the scalar output (harness poisons d_out with 0xAA before each launch).
__global__ void zero_kernel(float* __restrict__ out) {
    if (threadIdx.x == 0) out[0] = 0.0f;
}

// Per batch: stable compaction of indices j in [0, WL_) where mask[b][j] != 0,
// written in increasing-j order to pos[b][0..K_). One block per batch,
// 1024 threads, each owning a contiguous 64-element segment.
__global__ __launch_bounds__(1024) void pos_kernel(const int* __restrict__ mask,
                                                   int* __restrict__ pos) {
    const int b = blockIdx.x;
    const int t = threadIdx.x;            // 0..1023
    const int SEG = WL_ / 1024;           // 64
    const int* m = mask + (size_t)b * WL_;
    const int base = t * SEG;

    // Pass 1: count ones in my segment (int4 vector loads, 16B each).
    int cnt = 0;
    const int4* m4 = (const int4*)(m + base);
    #pragma unroll
    for (int i = 0; i < SEG / 4; ++i) {
        int4 v = m4[i];
        cnt += (v.x != 0) + (v.y != 0) + (v.z != 0) + (v.w != 0);
    }

    // Block-wide inclusive scan (Hillis-Steele) over 1024 counts.
    __shared__ int s[1024];
    s[t] = cnt;
    __syncthreads();
    for (int off = 1; off < 1024; off <<= 1) {
        int v = (t >= off) ? s[t - off] : 0;
        __syncthreads();
        s[t] += v;
        __syncthreads();
    }
    const int excl = s[t] - cnt;   // exclusive prefix = my write base

    // Pass 2: write positions (segment data is L2-warm from pass 1).
    int* p = pos + b * K_;
    int w = excl;
    for (int i = 0; i < SEG && w < K_; ++i) {
        if (m[base + i] != 0) {
            p[w] = base + i;
            ++w;
        }
    }
}

// One thread per (b,h,k): diff^2, block-reduce, one atomicAdd per block.
__global__ __launch_bounds__(256) void mse_kernel(const float* __restrict__ cs,
                                                  const float* __restrict__ csp,
                                                  const int* __restrict__ pos,
                                                  float* __restrict__ out) {
    const int idx = blockIdx.x * 256 + threadIdx.x;
    float v = 0.0f;
    if (idx < BHK) {
        const int k  = idx % K_;
        const int bh = idx / K_;          // = b*H_ + h
        const int b  = bh / H_;
        const float a = cs[(size_t)bh * LP_ + k];          // k < 384 => non-NaN
        const int   p = pos[b * K_ + k];
        const float c = csp[(size_t)bh * WL_ + p];
        const float d = a - c;
        v = d * d;
    }

    // Wave (64-lane) shuffle reduction.
    #pragma unroll
    for (int off = 32; off > 0; off >>= 1) v += __shfl_down(v, off, 64);

    __shared__ float s[4];
    const int lane = threadIdx.x & 63;
    const int wid  = threadIdx.x >> 6;
    if (lane == 0) s[wid] = v;
    __syncthreads();
    if (threadIdx.x == 0) {
        const float sum = s[0] + s[1] + s[2] + s[3];
        atomicAdd(out, sum * (1.0f / (float)BHK));
    }
}

extern "C" void kernel_launch(void* const* d_in, const int* in_sizes, int n_in,
                              void* d_out, int out_size, void* d_ws, size_t ws_size,
                              hipStream_t stream) {
    const float* cs   = (const float*)d_in[0];   // (B, H, LP) f32, NaN for k>=384
    const float* csp  = (const float*)d_in[1];   // (B, H, W, L) f32
    const int*   mask = (const int*)d_in[2];     // (B, W, L) i32, exactly K ones/batch
    float* out = (float*)d_out;                  // scalar f32
    int*   pos = (int*)d_ws;                     // B_*K_ ints = 24576 B scratch

    zero_kernel<<<1, 64, 0, stream>>>(out);
    pos_kernel<<<B_, 1024, 0, stream>>>(mask, pos);
    mse_kernel<<<(BHK + 255) / 256, 256, 0, stream>>>(cs, csp, pos, out);
}

// Round 2
// 441.409 us; speedup vs baseline: 1.1170x; 1.1170x over previous
//
#include <hip/hip_runtime.h>

// Problem constants: B=16, H=90, LP=512, W=256, L=256, K=384
#define B_     16
#define H_     90
#define LP_    512
#define WL_    65536        // W*L
#define K_     384
#define BHK    (B_ * H_ * K_)   // 552960
#define CHUNK  1024         // mask ints per block in count/scatter
#define NCHUNK (WL_ / CHUNK)    // 64 chunks per batch
#define NBLK   (B_ * NCHUNK)    // 1024 blocks

// K1: per-chunk popcount of mask; also zero the output scalar.
// grid = NBLK blocks x 256 threads; each thread loads int4 (16B) -> 4 KB/block.
__global__ __launch_bounds__(256) void count_kernel(const int* __restrict__ mask,
                                                    int* __restrict__ cnt,
                                                    float* __restrict__ out) {
    if (blockIdx.x == 0 && threadIdx.x == 0) out[0] = 0.0f;
    const int4 v = ((const int4*)(mask + (size_t)blockIdx.x * CHUNK))[threadIdx.x];
    int c = (v.x != 0) + (v.y != 0) + (v.z != 0) + (v.w != 0);
    #pragma unroll
    for (int off = 32; off > 0; off >>= 1) c += __shfl_down(c, off, 64);
    __shared__ int s[4];
    const int lane = threadIdx.x & 63, wid = threadIdx.x >> 6;
    if (lane == 0) s[wid] = c;
    __syncthreads();
    if (threadIdx.x == 0) cnt[blockIdx.x] = s[0] + s[1] + s[2] + s[3];
}

// K2: exclusive scan of chunk counts, segmented per batch.
// 1 block x 1024 threads = 16 waves; wave b scans batch b's 64 counts via shfl.
__global__ __launch_bounds__(1024) void scan_kernel(const int* __restrict__ cnt,
                                                    int* __restrict__ offs) {
    const int t = threadIdx.x;        // t = b*64 + chunk
    const int lane = t & 63;
    const int c = cnt[t];
    int incl = c;
    #pragma unroll
    for (int d = 1; d < 64; d <<= 1) {
        const int x = __shfl_up(incl, d, 64);
        if (lane >= d) incl += x;
    }
    offs[t] = incl - c;               // exclusive prefix within batch
}

// K3: scatter — re-read chunk (L2-warm), block-wide stable compaction.
// grid = NBLK blocks x 256 threads.
__global__ __launch_bounds__(256) void scatter_kernel(const int* __restrict__ mask,
                                                      const int* __restrict__ offs,
                                                      int* __restrict__ pos) {
    const int blk = blockIdx.x;
    const int b = blk >> 6;                       // blk / NCHUNK
    const int t = threadIdx.x;
    const int4 v = ((const int4*)(mask + (size_t)blk * CHUNK))[t];
    const int f0 = v.x != 0, f1 = v.y != 0, f2 = v.z != 0, f3 = v.w != 0;
    const int c = f0 + f1 + f2 + f3;

    // block-wide exclusive scan of per-thread counts (4 waves)
    const int lane = t & 63, wid = t >> 6;
    int incl = c;
    #pragma unroll
    for (int d = 1; d < 64; d <<= 1) {
        const int x = __shfl_up(incl, d, 64);
        if (lane >= d) incl += x;
    }
    __shared__ int ws[4];
    if (lane == 63) ws[wid] = incl;
    __syncthreads();
    int wbase = 0;
    for (int wi = 0; wi < wid; ++wi) wbase += ws[wi];
    const int excl = wbase + incl - c;

    const int gbase = (blk & 63) * CHUNK + t * 4; // index within batch's WL_ row
    int w = offs[blk] + excl;                     // rank within batch, 0..K_-1
    int* __restrict__ p = pos + b * K_;
    if (f0) p[w++] = gbase + 0;
    if (f1) p[w++] = gbase + 1;
    if (f2) p[w++] = gbase + 2;
    if (f3) p[w]   = gbase + 3;
}

// K4: MSE. One block per (b,h) row, 384 threads (= K_), thread k handles col k.
__global__ __launch_bounds__(384) void mse_kernel(const float* __restrict__ cs,
                                                  const float* __restrict__ csp,
                                                  const int* __restrict__ pos,
                                                  float* __restrict__ out) {
    const int bh = blockIdx.x;                    // 0..B_*H_-1
    const int b  = bh / H_;
    const int k  = threadIdx.x;                   // 0..383 (< LP_, non-NaN cols)
    const float a = cs[(size_t)bh * LP_ + k];
    const int   p = pos[b * K_ + k];
    const float cpv = csp[(size_t)bh * WL_ + p];
    const float d = a - cpv;
    float v = d * d;
    #pragma unroll
    for (int off = 32; off > 0; off >>= 1) v += __shfl_down(v, off, 64);
    __shared__ float s[6];
    const int lane = k & 63, wid = k >> 6;
    if (lane == 0) s[wid] = v;
    __syncthreads();
    if (k == 0) {
        const float sum = s[0] + s[1] + s[2] + s[3] + s[4] + s[5];
        atomicAdd(out, sum * (1.0f / (float)BHK));
    }
}

extern "C" void kernel_launch(void* const* d_in, const int* in_sizes, int n_in,
                              void* d_out, int out_size, void* d_ws, size_t ws_size,
                              hipStream_t stream) {
    const float* cs   = (const float*)d_in[0];   // (B, H, LP) f32
    const float* csp  = (const float*)d_in[1];   // (B, H, W, L) f32
    const int*   mask = (const int*)d_in[2];     // (B, W, L) i32, exactly K ones/batch
    float* out = (float*)d_out;                  // scalar f32

    // workspace layout
    int* pos  = (int*)d_ws;                      // B_*K_   = 6144 ints
    int* cnt  = pos + B_ * K_;                   // NBLK    = 1024 ints
    int* offs = cnt + NBLK;                      // NBLK    = 1024 ints

    count_kernel  <<<NBLK, 256, 0, stream>>>(mask, cnt, out);
    scan_kernel   <<<1, 1024, 0, stream>>>(cnt, offs);
    scatter_kernel<<<NBLK, 256, 0, stream>>>(mask, offs, pos);
    mse_kernel    <<<B_ * H_, 384, 0, stream>>>(cs, csp, pos, out);
}